// Round 1
// baseline (2553.640 us; speedup 1.0000x reference)
//
#include <hip/hip_runtime.h>
#include <math.h>

// Problem constants (from reference setup_inputs)
constexpr int  Bn  = 8;        // batch
constexpr int  Cin = 512;      // input channels
constexpr int  Nn  = 4096;     // H*W
constexpr int  Ck  = 256;      // key/query channels
constexpr int  Cv  = 256;      // value channels
constexpr int  Co  = 512;      // output channels

// d_out layout: [out | feat | feat | value]
constexpr size_t OUT_OFF = 0;
constexpr size_t F1_OFF  = (size_t)Bn * Co * Nn;                 // 16777216
constexpr size_t F2_OFF  = F1_OFF + (size_t)Bn * Ck * Nn;        // 25165824
constexpr size_t VAL_OFF = F2_OFF + (size_t)Bn * Ck * Nn;        // 33554432

// ---------------------------------------------------------------------------
// Tiled SGEMM for 1x1 conv:  out[b][o][n] = sum_c W[o][c] * X[b][?][?] + bias[o]
//   XT=false: X layout [B, Cdim, Nn]  (x / value path)
//   XT=true : X layout [B, Nn, Cdim]  (ctx path, inner dim contiguous)
// 64x64 tile, 256 threads, 4x4 per thread, K-chunks of 16.
// ---------------------------------------------------------------------------
template <bool XT>
__global__ __launch_bounds__(256) void gemm_k(const float* __restrict__ X,
                                              const float* __restrict__ W,
                                              const float* __restrict__ bias,
                                              float* __restrict__ out,
                                              int Cdim, int Odim)
{
    const int b  = blockIdx.z;
    const int o0 = blockIdx.y * 64;
    const int n0 = blockIdx.x * 64;
    const int t  = threadIdx.x;
    const int tx = t & 15, ty = t >> 4;

    __shared__ float Wt[16][64];   // Wt[c][o]
    __shared__ float Xt[16][64];   // Xt[c][n]

    const float* Xb = X + (size_t)b * Cdim * Nn;  // same count for both layouts
    float acc[4][4] = {};

    for (int c0 = 0; c0 < Cdim; c0 += 16) {
        __syncthreads();
        {
            const int oo = t >> 2, cl = (t & 3) * 4;
            const float4 w4 = *(const float4*)(W + (size_t)(o0 + oo) * Cdim + c0 + cl);
            Wt[cl + 0][oo] = w4.x; Wt[cl + 1][oo] = w4.y;
            Wt[cl + 2][oo] = w4.z; Wt[cl + 3][oo] = w4.w;
            if (XT) {
                const int nn = oo;  // t>>2
                const float4 x4 = *(const float4*)(Xb + (size_t)(n0 + nn) * Cdim + c0 + cl);
                Xt[cl + 0][nn] = x4.x; Xt[cl + 1][nn] = x4.y;
                Xt[cl + 2][nn] = x4.z; Xt[cl + 3][nn] = x4.w;
            } else {
                const int cc = ty, nl = tx * 4;
                *(float4*)&Xt[cc][nl] =
                    *(const float4*)(Xb + (size_t)(c0 + cc) * Nn + n0 + nl);
            }
        }
        __syncthreads();
#pragma unroll
        for (int c = 0; c < 16; ++c) {
            const float4 wv = *(const float4*)&Wt[c][ty * 4];
            const float4 xv = *(const float4*)&Xt[c][tx * 4];
            const float wa[4] = {wv.x, wv.y, wv.z, wv.w};
            const float xa[4] = {xv.x, xv.y, xv.z, xv.w};
#pragma unroll
            for (int i = 0; i < 4; ++i)
#pragma unroll
                for (int j = 0; j < 4; ++j)
                    acc[i][j] = fmaf(wa[i], xa[j], acc[i][j]);
        }
    }

    float* Ob = out + ((size_t)b * Odim + o0) * Nn + n0;
#pragma unroll
    for (int i = 0; i < 4; ++i) {
        const int o = ty * 4 + i;
        const float bv = bias[o0 + o];
        const float4 r = make_float4(acc[i][0] + bv, acc[i][1] + bv,
                                     acc[i][2] + bv, acc[i][3] + bv);
        *(float4*)(Ob + (size_t)o * Nn + tx * 4) = r;
    }
}

// ---------------------------------------------------------------------------
// BN training stats: per-channel mean/biased-var over (B, N); fold with
// gamma/beta into scale/shift.  One block per channel.
// ---------------------------------------------------------------------------
__global__ __launch_bounds__(256) void bn_stats(const float* __restrict__ qk,
                                                const float* __restrict__ gamma,
                                                const float* __restrict__ beta,
                                                float* __restrict__ ss)
{
    const int o = blockIdx.x;
    const int t = threadIdx.x;
    float s = 0.f, sq = 0.f;
    for (int b = 0; b < Bn; ++b) {
        const float* p = qk + ((size_t)b * Ck + o) * Nn;
        for (int n = t * 4; n < Nn; n += 1024) {
            const float4 v = *(const float4*)(p + n);
            s  += v.x + v.y + v.z + v.w;
            sq += v.x * v.x + v.y * v.y + v.z * v.z + v.w * v.w;
        }
    }
    __shared__ float rs[256], rq[256];
    rs[t] = s; rq[t] = sq;
    __syncthreads();
    for (int off = 128; off > 0; off >>= 1) {
        if (t < off) { rs[t] += rs[t + off]; rq[t] += rq[t + off]; }
        __syncthreads();
    }
    if (t == 0) {
        const float cnt  = (float)(Bn * Nn);
        const float mean = rs[0] / cnt;
        const float var  = rq[0] / cnt - mean * mean;
        const float inv  = rsqrtf(var + 1e-5f);
        const float sc   = gamma[o] * inv;
        ss[o]       = sc;
        ss[256 + o] = beta[o] - mean * sc;
    }
}

// ---------------------------------------------------------------------------
// feat = relu(qk * scale[o] + shift[o]) -> write to both feat slots
// ---------------------------------------------------------------------------
__global__ __launch_bounds__(256) void bn_relu(const float* __restrict__ qk,
                                               const float* __restrict__ ss,
                                               float* __restrict__ f1,
                                               float* __restrict__ f2)
{
    const size_t tid = (size_t)blockIdx.x * 256 + threadIdx.x;
    const size_t idx = tid * 4;
    const int o = (int)((idx >> 12) & 255);   // (idx / Nn) % Ck
    const float sc = ss[o], sh = ss[256 + o];
    const float4 v = *(const float4*)(qk + idx);
    float4 r;
    r.x = fmaxf(v.x * sc + sh, 0.f);
    r.y = fmaxf(v.y * sc + sh, 0.f);
    r.z = fmaxf(v.z * sc + sh, 0.f);
    r.w = fmaxf(v.w * sc + sh, 0.f);
    *(float4*)(f1 + idx) = r;
    *(float4*)(f2 + idx) = r;
}

// ---------------------------------------------------------------------------
// Flash attention (fp32):
//   sim = softmax(Q K / 16), ctx = sim V
//   Q[i][ck] = feat[b][ck][i0+i],  K[ck][j] = feat[b][ck][j],
//   V[j][cv] = value[b][cv][j].
// Per block: 64 Q rows, 256 threads; loop 64-col KV tiles with online softmax.
// Phase A thread map: (ty=t>>4 rows*4, tx=t&15 cols*4) -> s[4][4]
// Phase C thread map: rows (t>>4)*4+i, cols (t&15)*4 + 64k -> acc[4][4] float4
// ctx written as [B, Nn, Cv] (row-major per attention row).
// ---------------------------------------------------------------------------
__global__ __launch_bounds__(256) void attn(const float* __restrict__ feat,
                                            const float* __restrict__ value,
                                            float* __restrict__ ctx)
{
    const int b  = blockIdx.y;
    const int i0 = blockIdx.x * 64;
    const int t  = threadIdx.x;
    const int tx = t & 15, ty = t >> 4;

    __shared__ float Qs[32][64];        // 8 KB  Q chunk   [ck][i]
    __shared__ float Ks[32][64];        // 8 KB  K chunk   [ck][j]
    __shared__ float Ps[64][68];        // 17 KB P tile    [i][j] (pad 68: 2-way reads)
    __shared__ float Vs[16][260];       // 16.6 KB V chunk [jj][cv] (pad 260)
    __shared__ float mrow[64], lrow[64], arow[64];

    const float* F = feat  + (size_t)b * Ck * Nn;
    const float* V = value + (size_t)b * Cv * Nn;

    if (t < 64) { mrow[t] = -1e30f; lrow[t] = 0.f; }

    float4 acc[4][4];
#pragma unroll
    for (int i = 0; i < 4; ++i)
#pragma unroll
        for (int k = 0; k < 4; ++k) acc[i][k] = make_float4(0.f, 0.f, 0.f, 0.f);

    __syncthreads();

    for (int jt = 0; jt < Nn / 64; ++jt) {
        const int j0 = jt * 64;

        // ---- Phase A: s = (Q^T K) / 16 for this 64x64 tile
        float s[4][4] = {};
        for (int c0 = 0; c0 < Ck; c0 += 32) {
            __syncthreads();
#pragma unroll
            for (int p = 0; p < 2; ++p) {
                const int cc = p * 16 + ty;
                const int jx = tx * 4;
                *(float4*)&Qs[cc][jx] =
                    *(const float4*)(F + (size_t)(c0 + cc) * Nn + i0 + jx);
                *(float4*)&Ks[cc][jx] =
                    *(const float4*)(F + (size_t)(c0 + cc) * Nn + j0 + jx);
            }
            __syncthreads();
#pragma unroll 8
            for (int cc = 0; cc < 32; ++cc) {
                const float4 qv = *(const float4*)&Qs[cc][ty * 4];
                const float4 kv = *(const float4*)&Ks[cc][tx * 4];
                const float qa[4] = {qv.x, qv.y, qv.z, qv.w};
                const float ka[4] = {kv.x, kv.y, kv.z, kv.w};
#pragma unroll
                for (int i = 0; i < 4; ++i)
#pragma unroll
                    for (int j = 0; j < 4; ++j)
                        s[i][j] = fmaf(qa[i], ka[j], s[i][j]);
            }
        }
#pragma unroll
        for (int i = 0; i < 4; ++i)
#pragma unroll
            for (int j = 0; j < 4; ++j) s[i][j] *= 0.0625f;

        // ---- Phase B: online softmax (row r = ty*4+i owned by 16 tx-lanes,
        //      consecutive within one wave -> shfl reductions are safe)
#pragma unroll
        for (int i = 0; i < 4; ++i) {
            const int r = ty * 4 + i;
            float m = fmaxf(fmaxf(s[i][0], s[i][1]), fmaxf(s[i][2], s[i][3]));
#pragma unroll
            for (int off = 8; off >= 1; off >>= 1)
                m = fmaxf(m, __shfl_xor(m, off, 64));
            const float mold = mrow[r];
            const float mnew = fmaxf(mold, m);
            float pj[4], sum = 0.f;
#pragma unroll
            for (int j = 0; j < 4; ++j) { pj[j] = __expf(s[i][j] - mnew); sum += pj[j]; }
#pragma unroll
            for (int off = 8; off >= 1; off >>= 1)
                sum += __shfl_xor(sum, off, 64);
            const float alpha = __expf(mold - mnew);
            if (tx == 0) {
                mrow[r] = mnew;
                lrow[r] = lrow[r] * alpha + sum;
                arow[r] = alpha;
            }
#pragma unroll
            for (int j = 0; j < 4; ++j) Ps[r][tx * 4 + j] = pj[j];
        }
        __syncthreads();

        // ---- Phase C: acc = acc*alpha + P V
        float al[4];
#pragma unroll
        for (int i = 0; i < 4; ++i) al[i] = arow[ty * 4 + i];
#pragma unroll
        for (int i = 0; i < 4; ++i)
#pragma unroll
            for (int k = 0; k < 4; ++k) {
                acc[i][k].x *= al[i]; acc[i][k].y *= al[i];
                acc[i][k].z *= al[i]; acc[i][k].w *= al[i];
            }

        for (int jj0 = 0; jj0 < 64; jj0 += 16) {
            __syncthreads();
#pragma unroll
            for (int p = 0; p < 16; ++p) {       // stage Vs[jj][cv]
                const int cv = p * 16 + ty;
                Vs[tx][cv] = V[(size_t)cv * Nn + j0 + jj0 + tx];
            }
            __syncthreads();
#pragma unroll
            for (int jj = 0; jj < 16; ++jj) {
                float pv[4];
#pragma unroll
                for (int i = 0; i < 4; ++i) pv[i] = Ps[ty * 4 + i][jj0 + jj];
#pragma unroll
                for (int k = 0; k < 4; ++k) {
                    const float4 vv = *(const float4*)&Vs[jj][tx * 4 + 64 * k];
#pragma unroll
                    for (int i = 0; i < 4; ++i) {
                        acc[i][k].x = fmaf(pv[i], vv.x, acc[i][k].x);
                        acc[i][k].y = fmaf(pv[i], vv.y, acc[i][k].y);
                        acc[i][k].z = fmaf(pv[i], vv.z, acc[i][k].z);
                        acc[i][k].w = fmaf(pv[i], vv.w, acc[i][k].w);
                    }
                }
            }
        }
    }

    // ---- epilogue: divide by softmax denominator, write ctx [B, Nn, Cv]
    __syncthreads();
    float inv[4];
#pragma unroll
    for (int i = 0; i < 4; ++i) inv[i] = 1.0f / lrow[ty * 4 + i];
    float* Cb = ctx + (size_t)b * Nn * Cv;
#pragma unroll
    for (int i = 0; i < 4; ++i) {
        const int row = i0 + ty * 4 + i;
#pragma unroll
        for (int k = 0; k < 4; ++k) {
            float4 o = acc[i][k];
            o.x *= inv[i]; o.y *= inv[i]; o.z *= inv[i]; o.w *= inv[i];
            *(float4*)(Cb + (size_t)row * Cv + tx * 4 + 64 * k) = o;
        }
    }
}

// ---------------------------------------------------------------------------
extern "C" void kernel_launch(void* const* d_in, const int* in_sizes, int n_in,
                              void* d_out, int out_size, void* d_ws, size_t ws_size,
                              hipStream_t stream)
{
    const float* x     = (const float*)d_in[0];
    const float* Wk    = (const float*)d_in[1];
    const float* bk    = (const float*)d_in[2];
    const float* gamma = (const float*)d_in[3];
    const float* beta  = (const float*)d_in[4];
    const float* Wv    = (const float*)d_in[5];
    const float* bv    = (const float*)d_in[6];
    const float* Ww    = (const float*)d_in[7];
    const float* bw    = (const float*)d_in[8];

    float* out = (float*)d_out;
    float* f1  = out + F1_OFF;
    float* f2  = out + F2_OFF;
    float* val = out + VAL_OFF;

    float* ctx = (float*)d_ws;                        // [B, Nn, Cv]
    float* ss  = ctx + (size_t)Bn * Nn * Cv;          // scale[256], shift[256]

    // 1) qk = Wk*x + bk  (stored in feat1 slot, overwritten by bn_relu)
    gemm_k<false><<<dim3(Nn / 64, Ck / 64, Bn), 256, 0, stream>>>(x, Wk, bk, f1, Cin, Ck);
    // 2) value = Wv*x + bv
    gemm_k<false><<<dim3(Nn / 64, Cv / 64, Bn), 256, 0, stream>>>(x, Wv, bv, val, Cin, Cv);
    // 3) BN stats (training: biased var over B,N per channel)
    bn_stats<<<Ck, 256, 0, stream>>>(f1, gamma, beta, ss);
    // 4) feat = relu(norm(qk)) -> feat1 (in-place) and feat2
    bn_relu<<<(Bn * Ck * Nn) / (256 * 4), 256, 0, stream>>>(f1, ss, f1, f2);
    // 5) flash attention -> ctx [B, Nn, Cv]
    attn<<<dim3(Nn / 64, Bn), 256, 0, stream>>>(f1, val, ctx);
    // 6) out = Ww*ctx^T + bw
    gemm_k<true><<<dim3(Nn / 64, Co / 64, Bn), 256, 0, stream>>>(ctx, Ww, bw, out, Cv, Co);
}

// Round 2
// 755.138 us; speedup vs baseline: 3.3817x; 3.3817x over previous
//
#include <hip/hip_runtime.h>
#include <math.h>

// Problem constants (from reference setup_inputs)
constexpr int  Bn  = 8;        // batch
constexpr int  Cin = 512;      // input channels
constexpr int  Nn  = 4096;     // H*W
constexpr int  Ck  = 256;      // key/query channels
constexpr int  Cv  = 256;      // value channels
constexpr int  Co  = 512;      // output channels

// d_out layout: [out | feat | feat | value]
constexpr size_t F1_OFF  = (size_t)Bn * Co * Nn;
constexpr size_t F2_OFF  = F1_OFF + (size_t)Bn * Ck * Nn;
constexpr size_t VAL_OFF = F2_OFF + (size_t)Bn * Ck * Nn;

typedef __attribute__((ext_vector_type(8)))  short  short8;   // 8 x bf16 frag
typedef __attribute__((ext_vector_type(16))) float  f32x16;   // 32x32 C/D frag
typedef __attribute__((ext_vector_type(8)))  ushort ushort8;

static __device__ __forceinline__ ushort f2bf(float f) {
    union { float f; unsigned u; } x; x.f = f;
    unsigned r = x.u + 0x7fffu + ((x.u >> 16) & 1u);   // RNE (no NaN inputs here)
    return (ushort)(r >> 16);
}

// ---------------------------------------------------------------------------
// Tiled fp32 SGEMM for 1x1 conv (unchanged from round 0)
// ---------------------------------------------------------------------------
template <bool XT>
__global__ __launch_bounds__(256) void gemm_k(const float* __restrict__ X,
                                              const float* __restrict__ W,
                                              const float* __restrict__ bias,
                                              float* __restrict__ out,
                                              int Cdim, int Odim)
{
    const int b  = blockIdx.z;
    const int o0 = blockIdx.y * 64;
    const int n0 = blockIdx.x * 64;
    const int t  = threadIdx.x;
    const int tx = t & 15, ty = t >> 4;

    __shared__ float Wt[16][64];
    __shared__ float Xt[16][64];

    const float* Xb = X + (size_t)b * Cdim * Nn;
    float acc[4][4] = {};

    for (int c0 = 0; c0 < Cdim; c0 += 16) {
        __syncthreads();
        {
            const int oo = t >> 2, cl = (t & 3) * 4;
            const float4 w4 = *(const float4*)(W + (size_t)(o0 + oo) * Cdim + c0 + cl);
            Wt[cl + 0][oo] = w4.x; Wt[cl + 1][oo] = w4.y;
            Wt[cl + 2][oo] = w4.z; Wt[cl + 3][oo] = w4.w;
            if (XT) {
                const int nn = oo;
                const float4 x4 = *(const float4*)(Xb + (size_t)(n0 + nn) * Cdim + c0 + cl);
                Xt[cl + 0][nn] = x4.x; Xt[cl + 1][nn] = x4.y;
                Xt[cl + 2][nn] = x4.z; Xt[cl + 3][nn] = x4.w;
            } else {
                const int cc = ty, nl = tx * 4;
                *(float4*)&Xt[cc][nl] =
                    *(const float4*)(Xb + (size_t)(c0 + cc) * Nn + n0 + nl);
            }
        }
        __syncthreads();
#pragma unroll
        for (int c = 0; c < 16; ++c) {
            const float4 wv = *(const float4*)&Wt[c][ty * 4];
            const float4 xv = *(const float4*)&Xt[c][tx * 4];
            const float wa[4] = {wv.x, wv.y, wv.z, wv.w};
            const float xa[4] = {xv.x, xv.y, xv.z, xv.w};
#pragma unroll
            for (int i = 0; i < 4; ++i)
#pragma unroll
                for (int j = 0; j < 4; ++j)
                    acc[i][j] = fmaf(wa[i], xa[j], acc[i][j]);
        }
    }

    float* Ob = out + ((size_t)b * Odim + o0) * Nn + n0;
#pragma unroll
    for (int i = 0; i < 4; ++i) {
        const int o = ty * 4 + i;
        const float bv = bias[o0 + o];
        const float4 r = make_float4(acc[i][0] + bv, acc[i][1] + bv,
                                     acc[i][2] + bv, acc[i][3] + bv);
        *(float4*)(Ob + (size_t)o * Nn + tx * 4) = r;
    }
}

// ---------------------------------------------------------------------------
// BN training stats (unchanged)
// ---------------------------------------------------------------------------
__global__ __launch_bounds__(256) void bn_stats(const float* __restrict__ qk,
                                                const float* __restrict__ gamma,
                                                const float* __restrict__ beta,
                                                float* __restrict__ ss)
{
    const int o = blockIdx.x;
    const int t = threadIdx.x;
    float s = 0.f, sq = 0.f;
    for (int b = 0; b < Bn; ++b) {
        const float* p = qk + ((size_t)b * Ck + o) * Nn;
        for (int n = t * 4; n < Nn; n += 1024) {
            const float4 v = *(const float4*)(p + n);
            s  += v.x + v.y + v.z + v.w;
            sq += v.x * v.x + v.y * v.y + v.z * v.z + v.w * v.w;
        }
    }
    __shared__ float rs[256], rq[256];
    rs[t] = s; rq[t] = sq;
    __syncthreads();
    for (int off = 128; off > 0; off >>= 1) {
        if (t < off) { rs[t] += rs[t + off]; rq[t] += rq[t + off]; }
        __syncthreads();
    }
    if (t == 0) {
        const float cnt  = (float)(Bn * Nn);
        const float mean = rs[0] / cnt;
        const float var  = rq[0] / cnt - mean * mean;
        const float inv  = rsqrtf(var + 1e-5f);
        const float sc   = gamma[o] * inv;
        ss[o]       = sc;
        ss[256 + o] = beta[o] - mean * sc;
    }
}

// ---------------------------------------------------------------------------
// feat = relu(qk * scale + shift) -> both fp32 feat slots (unchanged)
// ---------------------------------------------------------------------------
__global__ __launch_bounds__(256) void bn_relu(const float* __restrict__ qk,
                                               const float* __restrict__ ss,
                                               float* __restrict__ f1,
                                               float* __restrict__ f2)
{
    const size_t tid = (size_t)blockIdx.x * 256 + threadIdx.x;
    const size_t idx = tid * 4;
    const int o = (int)((idx >> 12) & 255);
    const float sc = ss[o], sh = ss[256 + o];
    const float4 v = *(const float4*)(qk + idx);
    float4 r;
    r.x = fmaxf(v.x * sc + sh, 0.f);
    r.y = fmaxf(v.y * sc + sh, 0.f);
    r.z = fmaxf(v.z * sc + sh, 0.f);
    r.w = fmaxf(v.w * sc + sh, 0.f);
    *(float4*)(f1 + idx) = r;
    *(float4*)(f2 + idx) = r;
}

// ---------------------------------------------------------------------------
// feat fp32 [B][Ck][Nn] -> featT bf16 [B][Nn][Ck]  (LDS transpose, 64x64 tile)
// ---------------------------------------------------------------------------
__global__ __launch_bounds__(256) void transpose_bf16(const float* __restrict__ src,
                                                      ushort* __restrict__ dst)
{
    const int b  = blockIdx.z;
    const int c0 = blockIdx.y * 64;
    const int n0 = blockIdx.x * 64;
    const int t  = threadIdx.x;
    __shared__ float T[64][65];
#pragma unroll
    for (int p = 0; p < 16; ++p) {
        const int flat = p * 256 + t;
        const int cc = flat >> 6, nn = flat & 63;
        T[cc][nn] = src[((size_t)b * Ck + c0 + cc) * Nn + n0 + nn];
    }
    __syncthreads();
#pragma unroll
    for (int p = 0; p < 16; ++p) {
        const int flat = p * 256 + t;
        const int nn = flat >> 6, cc = flat & 63;
        dst[((size_t)b * Nn + n0 + nn) * Ck + c0 + cc] = f2bf(T[cc][nn]);
    }
}

// ---------------------------------------------------------------------------
// value fp32 [B][Cv][Nn] -> bf16 same layout
// ---------------------------------------------------------------------------
__global__ __launch_bounds__(256) void cast_bf16(const float* __restrict__ src,
                                                 ushort* __restrict__ dst)
{
    const size_t i8 = ((size_t)blockIdx.x * 256 + threadIdx.x) * 8;
    const float4 a = *(const float4*)(src + i8);
    const float4 b = *(const float4*)(src + i8 + 4);
    ushort8 o;
    o[0] = f2bf(a.x); o[1] = f2bf(a.y); o[2] = f2bf(a.z); o[3] = f2bf(a.w);
    o[4] = f2bf(b.x); o[5] = f2bf(b.y); o[6] = f2bf(b.z); o[7] = f2bf(b.w);
    *(ushort8*)(dst + i8) = o;
}

// ---------------------------------------------------------------------------
// bf16 MFMA flash attention, no-max softmax (scores provably >= 0, <= ~33).
//   featT [B][Nn][Ck] bf16 : Q rows and K rows (both A/B-frag friendly)
//   valB  [B][Cv][Nn] bf16 : V as B^T for the PV matmul
//   ctx   [B][Nn][Cv] fp32
// Block: 256 thr = 4 waves, 64 Q-rows, KV tile = 64 cols.
//   wave w: rows (w>>1)*32..+31 ; QK j-half (w&1)*32 ; PV cv-half (w&1)*128
// Row sums via MFMA against all-ones B (row-aligned with O accumulator).
// ---------------------------------------------------------------------------
__global__ __launch_bounds__(256, 2) void attn_mfma(const ushort* __restrict__ featT,
                                                    const ushort* __restrict__ valB,
                                                    float* __restrict__ ctx)
{
    const int b   = blockIdx.y;
    const int i0  = blockIdx.x * 64;
    const int t   = threadIdx.x;
    const int w   = t >> 6;
    const int L   = t & 63;
    const int l31 = L & 31, hl = L >> 5;
    const int row0 = (w >> 1) * 32;
    const int jsel = (w & 1) * 32;
    const int cvb  = (w & 1) * 128;

    __shared__ __align__(16) short Ks[64][264];   // [j][c]  pad 8  (33.0 KB)
    __shared__ __align__(16) short Vs[256][72];   // [cv][j] pad 8  (36.0 KB)
    __shared__ __align__(16) short Ps[64][72];    // [i][j]  pad 8  ( 9.0 KB)

    const ushort* F = featT + (size_t)b * Nn * Ck;
    const ushort* V = valB  + (size_t)b * Cv * Nn;

    // Q fragments: rows i0+row0+l31, k-chunks of 16 (lane covers hl*8..+8)
    short8 Qf[16];
    {
        const ushort* qp = F + ((size_t)(i0 + row0 + l31)) * Ck + hl * 8;
#pragma unroll
        for (int kc = 0; kc < 16; ++kc)
            Qf[kc] = *(const short8*)(qp + kc * 16);
    }

    f32x16 Oacc[4];
    f32x16 lacc;
#pragma unroll
    for (int r = 0; r < 16; ++r) {
        lacc[r] = 0.f;
#pragma unroll
        for (int c = 0; c < 4; ++c) Oacc[c][r] = 0.f;
    }

    short8 ones8;
#pragma unroll
    for (int i = 0; i < 8; ++i) ones8[i] = (short)0x3f80;   // bf16 1.0

    constexpr float CEXP = 0.09016844005556021f;  // log2(e)/16

    for (int jt = 0; jt < Nn / 64; ++jt) {
        const int j0 = jt * 64;
        __syncthreads();
        // ---- stage K tile (contiguous 32 KB of featT rows j0..j0+63)
        {
            const ushort* src = F + (size_t)j0 * Ck;
#pragma unroll
            for (int p = 0; p < 8; ++p) {
                const int e = p * 256 + t;
                const short8 v = *(const short8*)(src + e * 8);
                *(short8*)&Ks[e >> 5][(e & 31) * 8] = v;
            }
        }
        // ---- stage V tile (256 rows x 64 cols from valB)
        {
#pragma unroll
            for (int p = 0; p < 8; ++p) {
                const int cv = p * 32 + (t >> 3);
                const int jc = (t & 7) * 8;
                const short8 v = *(const short8*)(V + (size_t)cv * Nn + j0 + jc);
                *(short8*)&Vs[cv][jc] = v;
            }
        }
        __syncthreads();

        // ---- QK: S (32 rows x 32 cols per wave), K = 256 in 16 chunks
        f32x16 S;
#pragma unroll
        for (int r = 0; r < 16; ++r) S[r] = 0.f;
#pragma unroll
        for (int kc = 0; kc < 16; ++kc) {
            const short8 Kf = *(const short8*)&Ks[jsel + l31][kc * 16 + hl * 8];
            S = __builtin_amdgcn_mfma_f32_32x32x16_bf16(Qf[kc], Kf, S, 0, 0, 0);
        }

        // ---- softmax numerator (no max subtraction), P -> LDS as bf16
#pragma unroll
        for (int r = 0; r < 16; ++r) {
            const float p = exp2f(S[r] * CEXP);
            const int row = row0 + (r & 3) + 8 * (r >> 2) + 4 * hl;
            Ps[row][jsel + l31] = (short)f2bf(p);
        }
        __syncthreads();

        // ---- PV: O += P V, l += P 1   (K-dim = 64 in 4 chunks of 16)
#pragma unroll
        for (int kj = 0; kj < 4; ++kj) {
            const short8 Pf = *(const short8*)&Ps[row0 + l31][kj * 16 + hl * 8];
            lacc = __builtin_amdgcn_mfma_f32_32x32x16_bf16(Pf, ones8, lacc, 0, 0, 0);
#pragma unroll
            for (int cvt = 0; cvt < 4; ++cvt) {
                const short8 Vf =
                    *(const short8*)&Vs[cvb + cvt * 32 + l31][kj * 16 + hl * 8];
                Oacc[cvt] =
                    __builtin_amdgcn_mfma_f32_32x32x16_bf16(Pf, Vf, Oacc[cvt], 0, 0, 0);
            }
        }
    }

    // ---- epilogue: ctx[row][cv] = O / l   (l rows align with O rows per reg)
    float* C = ctx + ((size_t)b * Nn + i0 + row0) * Cv + cvb;
#pragma unroll
    for (int r = 0; r < 16; ++r) {
        const float linv = 1.0f / lacc[r];
        const int row = (r & 3) + 8 * (r >> 2) + 4 * hl;
        float* cp = C + (size_t)row * Cv + l31;
#pragma unroll
        for (int cvt = 0; cvt < 4; ++cvt)
            cp[cvt * 32] = Oacc[cvt][r] * linv;
    }
}

// ---------------------------------------------------------------------------
extern "C" void kernel_launch(void* const* d_in, const int* in_sizes, int n_in,
                              void* d_out, int out_size, void* d_ws, size_t ws_size,
                              hipStream_t stream)
{
    const float* x     = (const float*)d_in[0];
    const float* Wk    = (const float*)d_in[1];
    const float* bk    = (const float*)d_in[2];
    const float* gamma = (const float*)d_in[3];
    const float* beta  = (const float*)d_in[4];
    const float* Wv    = (const float*)d_in[5];
    const float* bv    = (const float*)d_in[6];
    const float* Ww    = (const float*)d_in[7];
    const float* bw    = (const float*)d_in[8];

    float* out = (float*)d_out;
    float* f1  = out + F1_OFF;
    float* f2  = out + F2_OFF;
    float* val = out + VAL_OFF;

    float*  ctx   = (float*)d_ws;                          // [B,Nn,Cv] fp32
    float*  ss    = ctx + (size_t)Bn * Nn * Cv;            // 512 floats
    ushort* featT = (ushort*)(ss + 512);                   // [B,Nn,Ck] bf16
    ushort* valB  = featT + (size_t)Bn * Nn * Ck;          // [B,Cv,Nn] bf16

    // 1) qk = Wk*x + bk   (into feat1 slot)
    gemm_k<false><<<dim3(Nn / 64, Ck / 64, Bn), 256, 0, stream>>>(x, Wk, bk, f1, Cin, Ck);
    // 2) value = Wv*x + bv
    gemm_k<false><<<dim3(Nn / 64, Cv / 64, Bn), 256, 0, stream>>>(x, Wv, bv, val, Cin, Cv);
    // 3) BN stats
    bn_stats<<<Ck, 256, 0, stream>>>(f1, gamma, beta, ss);
    // 4) feat = relu(norm(qk)) -> f1 (in place) and f2
    bn_relu<<<(Bn * Ck * Nn) / (256 * 4), 256, 0, stream>>>(f1, ss, f1, f2);
    // 5) bf16 packs for attention
    transpose_bf16<<<dim3(Nn / 64, Ck / 64, Bn), 256, 0, stream>>>(f1, featT);
    cast_bf16<<<(Bn * Cv * Nn) / (256 * 8), 256, 0, stream>>>(val, valB);
    // 6) flash attention (bf16 MFMA) -> ctx
    attn_mfma<<<dim3(Nn / 64, Bn), 256, 0, stream>>>(featT, valB, ctx);
    // 7) out = Ww*ctx^T + bw
    gemm_k<true><<<dim3(Nn / 64, Co / 64, Bn), 256, 0, stream>>>(ctx, Ww, bw, out, Cv, Co);
}

// Round 3
// 522.501 us; speedup vs baseline: 4.8873x; 1.4452x over previous
//
#include <hip/hip_runtime.h>
#include <math.h>

// Problem constants (from reference setup_inputs)
constexpr int  Bn  = 8;        // batch
constexpr int  Cin = 512;      // input channels
constexpr int  Nn  = 4096;     // H*W
constexpr int  Ck  = 256;      // key/query channels
constexpr int  Cv  = 256;      // value channels
constexpr int  Co  = 512;      // output channels

// d_out layout: [out | feat | feat | value]
constexpr size_t F1_OFF  = (size_t)Bn * Co * Nn;
constexpr size_t F2_OFF  = F1_OFF + (size_t)Bn * Ck * Nn;
constexpr size_t VAL_OFF = F2_OFF + (size_t)Bn * Ck * Nn;

typedef __attribute__((ext_vector_type(8)))  short  short8;   // 8 x bf16 frag
typedef __attribute__((ext_vector_type(16))) float  f32x16;   // 32x32 C/D frag
typedef __attribute__((ext_vector_type(8)))  ushort ushort8;

static __device__ __forceinline__ ushort f2bf(float f) {
    union { float f; unsigned u; } x; x.f = f;
    unsigned r = x.u + 0x7fffu + ((x.u >> 16) & 1u);   // RNE (no NaN inputs here)
    return (ushort)(r >> 16);
}

// ---------------------------------------------------------------------------
// Cast the three weight matrices to bf16 (all are 131072 elements).
// ---------------------------------------------------------------------------
__global__ __launch_bounds__(256) void cast_w(const float* __restrict__ a,
                                              const float* __restrict__ b,
                                              const float* __restrict__ c,
                                              ushort* __restrict__ da,
                                              ushort* __restrict__ db,
                                              ushort* __restrict__ dc)
{
    const int tid   = blockIdx.x * 256 + threadIdx.x;
    const int which = tid >> 14;                 // 16384 threads per matrix
    const int off   = (tid & 16383) * 8;
    const float* s = (which == 0) ? a : (which == 1) ? b : c;
    ushort*      d = (which == 0) ? da : (which == 1) ? db : dc;
    const float4 u = *(const float4*)(s + off);
    const float4 v = *(const float4*)(s + off + 4);
    ushort8 o;
    o[0] = f2bf(u.x); o[1] = f2bf(u.y); o[2] = f2bf(u.z); o[3] = f2bf(u.w);
    o[4] = f2bf(v.x); o[5] = f2bf(v.y); o[6] = f2bf(v.z); o[7] = f2bf(v.w);
    *(ushort8*)(d + off) = o;
}

// ---------------------------------------------------------------------------
// src fp32 [B][C][Nn] -> dst bf16 [B][Nn][C]  (LDS transpose, 64x64 tile)
// ---------------------------------------------------------------------------
__global__ __launch_bounds__(256) void transpose_c(const float* __restrict__ src,
                                                   ushort* __restrict__ dst, int C)
{
    const int b  = blockIdx.z;
    const int c0 = blockIdx.y * 64;
    const int n0 = blockIdx.x * 64;
    const int t  = threadIdx.x;
    __shared__ float T[64][65];
#pragma unroll
    for (int p = 0; p < 16; ++p) {
        const int flat = p * 256 + t;
        const int cc = flat >> 6, nn = flat & 63;
        T[cc][nn] = src[((size_t)b * C + c0 + cc) * Nn + n0 + nn];
    }
    __syncthreads();
#pragma unroll
    for (int p = 0; p < 16; ++p) {
        const int flat = p * 256 + t;
        const int nn = flat >> 6, cc = flat & 63;
        dst[((size_t)b * Nn + n0 + nn) * C + c0 + cc] = f2bf(T[cc][nn]);
    }
}

// ---------------------------------------------------------------------------
// bf16 MFMA GEMM for the 1x1 convs:
//   out[b][m][n] (+ optional bf16 copy) = sum_k Wb[m][k] * XT[b][n][k] + bias[m]
// Block 256 thr = 4 waves; tile 128(m) x 128(n); wave = 64x64 = 2x2 of 32x32.
// LDS rows padded to 72 shorts (144B == 4 words mod 32 -> conflict-free).
// ---------------------------------------------------------------------------
template <int K, bool DUAL>
__global__ __launch_bounds__(256) void gemm_bf(const ushort* __restrict__ XT,
                                               const ushort* __restrict__ Wb,
                                               const float*  __restrict__ bias,
                                               float* __restrict__ out,
                                               ushort* __restrict__ out_bf,
                                               int M)
{
    const int b  = blockIdx.z;
    const int m0 = blockIdx.y * 128;
    const int n0 = blockIdx.x * 128;
    const int t  = threadIdx.x;
    const int w  = t >> 6, L = t & 63;
    const int l31 = L & 31, hl = L >> 5;
    const int wm = (w >> 1) * 64, wn = (w & 1) * 64;

    __shared__ __align__(16) short As[128][72];   // [m][k]
    __shared__ __align__(16) short Bs[128][72];   // [n][k]

    const ushort* Xb = XT + (size_t)b * Nn * K;

    f32x16 acc[2][2];
#pragma unroll
    for (int a = 0; a < 2; ++a)
#pragma unroll
        for (int bb = 0; bb < 2; ++bb)
#pragma unroll
            for (int r = 0; r < 16; ++r) acc[a][bb][r] = 0.f;

    for (int k0 = 0; k0 < K; k0 += 64) {
        __syncthreads();
#pragma unroll
        for (int p = 0; p < 4; ++p) {            // stage 128x64 A and B tiles
            const int e   = p * 256 + t;
            const int row = e >> 3, ko = (e & 7) * 8;
            *(short8*)&As[row][ko] =
                *(const short8*)(Wb + (size_t)(m0 + row) * K + k0 + ko);
            *(short8*)&Bs[row][ko] =
                *(const short8*)(Xb + (size_t)(n0 + row) * K + k0 + ko);
        }
        __syncthreads();
#pragma unroll
        for (int kc = 0; kc < 4; ++kc) {
            short8 Af[2], Bf[2];
#pragma unroll
            for (int a = 0; a < 2; ++a)
                Af[a] = *(const short8*)&As[wm + a * 32 + l31][kc * 16 + hl * 8];
#pragma unroll
            for (int bb = 0; bb < 2; ++bb)
                Bf[bb] = *(const short8*)&Bs[wn + bb * 32 + l31][kc * 16 + hl * 8];
#pragma unroll
            for (int a = 0; a < 2; ++a)
#pragma unroll
                for (int bb = 0; bb < 2; ++bb)
                    acc[a][bb] = __builtin_amdgcn_mfma_f32_32x32x16_bf16(
                        Af[a], Bf[bb], acc[a][bb], 0, 0, 0);
        }
    }

    // epilogue: D row=(r&3)+8*(r>>2)+4*hl, col=l31
#pragma unroll
    for (int a = 0; a < 2; ++a)
#pragma unroll
        for (int r = 0; r < 16; ++r) {
            const int row = (r & 3) + 8 * (r >> 2) + 4 * hl;
            const int o   = m0 + wm + a * 32 + row;
            const float bv = bias[o];
            const size_t base = ((size_t)b * M + o) * Nn + n0 + wn + l31;
#pragma unroll
            for (int bb = 0; bb < 2; ++bb) {
                const float vv = acc[a][bb][r] + bv;
                out[base + bb * 32] = vv;
                if (DUAL) out_bf[base + bb * 32] = f2bf(vv);
            }
        }
}

// ---------------------------------------------------------------------------
// BN training stats (unchanged)
// ---------------------------------------------------------------------------
__global__ __launch_bounds__(256) void bn_stats(const float* __restrict__ qk,
                                                const float* __restrict__ gamma,
                                                const float* __restrict__ beta,
                                                float* __restrict__ ss)
{
    const int o = blockIdx.x;
    const int t = threadIdx.x;
    float s = 0.f, sq = 0.f;
    for (int b = 0; b < Bn; ++b) {
        const float* p = qk + ((size_t)b * Ck + o) * Nn;
        for (int n = t * 4; n < Nn; n += 1024) {
            const float4 v = *(const float4*)(p + n);
            s  += v.x + v.y + v.z + v.w;
            sq += v.x * v.x + v.y * v.y + v.z * v.z + v.w * v.w;
        }
    }
    __shared__ float rs[256], rq[256];
    rs[t] = s; rq[t] = sq;
    __syncthreads();
    for (int off = 128; off > 0; off >>= 1) {
        if (t < off) { rs[t] += rs[t + off]; rq[t] += rq[t + off]; }
        __syncthreads();
    }
    if (t == 0) {
        const float cnt  = (float)(Bn * Nn);
        const float mean = rs[0] / cnt;
        const float var  = rq[0] / cnt - mean * mean;
        const float inv  = rsqrtf(var + 1e-5f);
        const float sc   = gamma[o] * inv;
        ss[o]       = sc;
        ss[256 + o] = beta[o] - mean * sc;
    }
}

// ---------------------------------------------------------------------------
// feat = relu(qk * scale + shift) -> both fp32 feat slots (unchanged)
// ---------------------------------------------------------------------------
__global__ __launch_bounds__(256) void bn_relu(const float* __restrict__ qk,
                                               const float* __restrict__ ss,
                                               float* __restrict__ f1,
                                               float* __restrict__ f2)
{
    const size_t tid = (size_t)blockIdx.x * 256 + threadIdx.x;
    const size_t idx = tid * 4;
    const int o = (int)((idx >> 12) & 255);
    const float sc = ss[o], sh = ss[256 + o];
    const float4 v = *(const float4*)(qk + idx);
    float4 r;
    r.x = fmaxf(v.x * sc + sh, 0.f);
    r.y = fmaxf(v.y * sc + sh, 0.f);
    r.z = fmaxf(v.z * sc + sh, 0.f);
    r.w = fmaxf(v.w * sc + sh, 0.f);
    *(float4*)(f1 + idx) = r;
    *(float4*)(f2 + idx) = r;
}

// ---------------------------------------------------------------------------
// bf16 MFMA flash attention, no-max softmax (scores >= 0, <= ~33).
//   featT [B][Nn][Ck] bf16, valB [B][Cv][Nn] bf16, ctx OUT bf16 [B][Nn][Cv]
// (identical to round 2 except bf16 ctx store)
// ---------------------------------------------------------------------------
__global__ __launch_bounds__(256, 2) void attn_mfma(const ushort* __restrict__ featT,
                                                    const ushort* __restrict__ valB,
                                                    ushort* __restrict__ ctx)
{
    const int b   = blockIdx.y;
    const int i0  = blockIdx.x * 64;
    const int t   = threadIdx.x;
    const int w   = t >> 6;
    const int L   = t & 63;
    const int l31 = L & 31, hl = L >> 5;
    const int row0 = (w >> 1) * 32;
    const int jsel = (w & 1) * 32;
    const int cvb  = (w & 1) * 128;

    __shared__ __align__(16) short Ks[64][264];   // [j][c]  pad 8
    __shared__ __align__(16) short Vs[256][72];   // [cv][j] pad 8
    __shared__ __align__(16) short Ps[64][72];    // [i][j]  pad 8

    const ushort* F = featT + (size_t)b * Nn * Ck;
    const ushort* V = valB  + (size_t)b * Cv * Nn;

    short8 Qf[16];
    {
        const ushort* qp = F + ((size_t)(i0 + row0 + l31)) * Ck + hl * 8;
#pragma unroll
        for (int kc = 0; kc < 16; ++kc)
            Qf[kc] = *(const short8*)(qp + kc * 16);
    }

    f32x16 Oacc[4];
    f32x16 lacc;
#pragma unroll
    for (int r = 0; r < 16; ++r) {
        lacc[r] = 0.f;
#pragma unroll
        for (int c = 0; c < 4; ++c) Oacc[c][r] = 0.f;
    }

    short8 ones8;
#pragma unroll
    for (int i = 0; i < 8; ++i) ones8[i] = (short)0x3f80;   // bf16 1.0

    constexpr float CEXP = 0.09016844005556021f;  // log2(e)/16

    for (int jt = 0; jt < Nn / 64; ++jt) {
        const int j0 = jt * 64;
        __syncthreads();
        {
            const ushort* src = F + (size_t)j0 * Ck;
#pragma unroll
            for (int p = 0; p < 8; ++p) {
                const int e = p * 256 + t;
                const short8 v = *(const short8*)(src + e * 8);
                *(short8*)&Ks[e >> 5][(e & 31) * 8] = v;
            }
        }
        {
#pragma unroll
            for (int p = 0; p < 8; ++p) {
                const int cv = p * 32 + (t >> 3);
                const int jc = (t & 7) * 8;
                const short8 v = *(const short8*)(V + (size_t)cv * Nn + j0 + jc);
                *(short8*)&Vs[cv][jc] = v;
            }
        }
        __syncthreads();

        f32x16 S;
#pragma unroll
        for (int r = 0; r < 16; ++r) S[r] = 0.f;
#pragma unroll
        for (int kc = 0; kc < 16; ++kc) {
            const short8 Kf = *(const short8*)&Ks[jsel + l31][kc * 16 + hl * 8];
            S = __builtin_amdgcn_mfma_f32_32x32x16_bf16(Qf[kc], Kf, S, 0, 0, 0);
        }

#pragma unroll
        for (int r = 0; r < 16; ++r) {
            const float p = exp2f(S[r] * CEXP);
            const int row = row0 + (r & 3) + 8 * (r >> 2) + 4 * hl;
            Ps[row][jsel + l31] = (short)f2bf(p);
        }
        __syncthreads();

#pragma unroll
        for (int kj = 0; kj < 4; ++kj) {
            const short8 Pf = *(const short8*)&Ps[row0 + l31][kj * 16 + hl * 8];
            lacc = __builtin_amdgcn_mfma_f32_32x32x16_bf16(Pf, ones8, lacc, 0, 0, 0);
#pragma unroll
            for (int cvt = 0; cvt < 4; ++cvt) {
                const short8 Vf =
                    *(const short8*)&Vs[cvb + cvt * 32 + l31][kj * 16 + hl * 8];
                Oacc[cvt] =
                    __builtin_amdgcn_mfma_f32_32x32x16_bf16(Pf, Vf, Oacc[cvt], 0, 0, 0);
            }
        }
    }

    // epilogue: ctx[row][cv] = bf16(O / l)
    __syncthreads();
    ushort* C = ctx + ((size_t)b * Nn + i0 + row0) * Cv + cvb;
#pragma unroll
    for (int r = 0; r < 16; ++r) {
        const float linv = 1.0f / lacc[r];
        const int row = (r & 3) + 8 * (r >> 2) + 4 * hl;
        ushort* cp = C + (size_t)row * Cv + l31;
#pragma unroll
        for (int cvt = 0; cvt < 4; ++cvt)
            cp[cvt * 32] = f2bf(Oacc[cvt][r] * linv);
    }
}

// ---------------------------------------------------------------------------
extern "C" void kernel_launch(void* const* d_in, const int* in_sizes, int n_in,
                              void* d_out, int out_size, void* d_ws, size_t ws_size,
                              hipStream_t stream)
{
    const float* x     = (const float*)d_in[0];
    const float* Wk    = (const float*)d_in[1];
    const float* bk    = (const float*)d_in[2];
    const float* gamma = (const float*)d_in[3];
    const float* beta  = (const float*)d_in[4];
    const float* Wv    = (const float*)d_in[5];
    const float* bv    = (const float*)d_in[6];
    const float* Ww    = (const float*)d_in[7];
    const float* bw    = (const float*)d_in[8];

    float* out = (float*)d_out;
    float* f1  = out + F1_OFF;
    float* f2  = out + F2_OFF;
    float* val = out + VAL_OFF;

    // workspace packing (51.1 MB), with aliasing over dead xT:
    //   xT    : [0 .. 16,777,216) ushorts   live steps 2-4
    //   featT : alias xT[0 .. 8,388,608)    live steps 7-8
    //   ctxb  : alias xT[8,388,608 .. )     live steps 8-9
    ushort* xT    = (ushort*)d_ws;                       // [B][Nn][Cin]
    ushort* featT = xT;                                  // [B][Nn][Ck]
    ushort* ctxb  = xT + (size_t)8388608;                // [B][Nn][Cv]
    ushort* valB  = xT + (size_t)16777216;               // [B][Cv][Nn]
    ushort* Wkb   = valB + (size_t)8388608;
    ushort* Wvb   = Wkb + 131072;
    ushort* Wwb   = Wvb + 131072;
    float*  ss    = (float*)(Wwb + 131072);              // 512 floats

    // 1) weights -> bf16
    cast_w<<<192, 256, 0, stream>>>(Wk, Wv, Ww, Wkb, Wvb, Wwb);
    // 2) x -> xT bf16 [B][Nn][Cin]
    transpose_c<<<dim3(Nn / 64, Cin / 64, Bn), 256, 0, stream>>>(x, xT, Cin);
    // 3) qk = Wk*x + bk (fp32, into feat1 slot)
    gemm_bf<512, false><<<dim3(Nn / 128, Ck / 128, Bn), 256, 0, stream>>>(
        xT, Wkb, bk, f1, nullptr, Ck);
    // 4) value = Wv*x + bv (fp32 output + bf16 copy for attention)
    gemm_bf<512, true><<<dim3(Nn / 128, Cv / 128, Bn), 256, 0, stream>>>(
        xT, Wvb, bv, val, valB, Cv);
    // 5) BN stats
    bn_stats<<<Ck, 256, 0, stream>>>(f1, gamma, beta, ss);
    // 6) feat = relu(norm(qk)) -> f1 (in place) and f2
    bn_relu<<<(Bn * Ck * Nn) / (256 * 4), 256, 0, stream>>>(f1, ss, f1, f2);
    // 7) feat -> featT bf16 [B][Nn][Ck]   (xT dead, aliased)
    transpose_c<<<dim3(Nn / 64, Ck / 64, Bn), 256, 0, stream>>>(f1, featT, Ck);
    // 8) flash attention -> ctx bf16 [B][Nn][Cv]
    attn_mfma<<<dim3(Nn / 64, Bn), 256, 0, stream>>>(featT, valB, ctxb);
    // 9) out = Ww*ctx + bw
    gemm_bf<256, false><<<dim3(Nn / 128, Co / 128, Bn), 256, 0, stream>>>(
        ctxb, Wwb, bw, out, nullptr, Co);
}